// Round 6
// baseline (1133.197 us; speedup 1.0000x reference)
//
#include <hip/hip_runtime.h>
#include <hip/hip_bf16.h>
#include <math.h>

#define B 4
#define A 256
#define NN 64
#define NCB 128
#define NF 128
#define NSB 50
#define BA (B*A)
#define PAIRS (BA*NN)
#define SLOTF 384          // floats of out_V per pair (128 channels x 3 dims)

// module-scope scratch: no d_ws dependency, never touches input buffers
__device__ float g_yi[BA*NF];        // xi @ in2f_W, fp32
__device__ float g_vik[BA*NCB*3];    // Vik rows, fp32, layout [row][c*3+d]

__device__ __forceinline__ float ssp(float x){
    return fmaxf(x, 0.f) + log1pf(expf(-fabsf(x))) - 0.6931471805599453f;
}

__device__ __forceinline__ float dot128(const float* __restrict__ s,
                                        const float* __restrict__ W, int tid){
    float acc = 0.f;
    #pragma unroll 16
    for (int k = 0; k < NF; k++) acc += s[k] * W[k*NF + tid];
    return acc;
}

// g_yi[row,f] = xi[row,:] @ in2f_W[:,f]
__global__ __launch_bounds__(NF)
void k_yi(const float* __restrict__ xi, const float* __restrict__ W){
    int row = blockIdx.x; int f = threadIdx.x;
    __shared__ float x[NCB];
    x[f] = xi[row*NCB + f];
    __syncthreads();
    float s = 0.f;
    #pragma unroll 16
    for (int c = 0; c < NCB; c++) s += x[c] * W[c*NF + f];
    g_yi[row*NF + f] = s;
}

__global__ __launch_bounds__(NF)
void k_main(const float* __restrict__ r_ij, const float* __restrict__ cos_ij,
            const float* __restrict__ f_ij, const float* __restrict__ mask,
            const int* __restrict__ neighbors,
            const float* __restrict__ fW1, const float* __restrict__ fb1,
            const float* __restrict__ fW2, const float* __restrict__ fb2,
            const float* __restrict__ f2W, const float* __restrict__ f2b,
            const float* __restrict__ aW1, const float* __restrict__ ab1,
            const float* __restrict__ aW2, const float* __restrict__ ab2,
            const float* __restrict__ pW1, const float* __restrict__ pb1,
            const float* __restrict__ pW2, const float* __restrict__ pb2,
            const float* __restrict__ eW1, const float* __restrict__ eb1,
            const float* __restrict__ eW2, const float* __restrict__ eb2,
            float* __restrict__ outV, float* __restrict__ out_vi){
    const int ba  = blockIdx.x;
    const int tid = threadIdx.x;
    const int b   = ba / A;

    __shared__ float fbuf[NSB];
    __shared__ float buf1[NF];
    __shared__ float buf2[NF];

    const float fb1r = fb1[tid], fb2r = fb2[tid];
    const float f2br = f2b[tid];
    const float pb1r = pb1[tid], pb2r = pb2[tid];
    const float eb1r = eb1[tid], eb2r = eb2[tid];

    float vik0 = 0.f, vik1 = 0.f, vik2 = 0.f, vsum = 0.f;

    for (int n = 0; n < NN; n++){
        const int p = ba*NN + n;

        __syncthreads();
        if (tid < NSB) fbuf[tid] = f_ij[p*NSB + tid];
        __syncthreads();

        float s = fb1r;
        #pragma unroll 10
        for (int k = 0; k < NSB; k++) s += fbuf[k] * fW1[k*NF + tid];
        const float h1 = ssp(s);

        __syncthreads();
        buf1[tid] = h1;
        __syncthreads();

        float wf = dot128(buf1, fW2, tid) + fb2r;
        const float r = r_ij[p];
        const float C = (r < 5.f) ? 0.5f * (cosf(r * 0.62831853071795864769f) + 1.f) : 0.f;
        wf *= C;

        const int j = neighbors[p] & (A-1);
        const float u = g_yi[(b*A + j)*NF + tid] * wf;

        __syncthreads();
        buf2[tid] = u;
        __syncthreads();

        const float v = ssp(dot128(buf2, f2W, tid) + f2br);
        const float m = mask[p];
        vsum += v * m;

        __syncthreads();
        buf1[tid] = v;                         // buf1 := v (pair & env reuse)
        __syncthreads();

        // pair branch
        const float hp = ssp(dot128(buf1, pW1, tid) + pb1r);
        __syncthreads();
        buf2[tid] = hp;
        __syncthreads();
        const float vijv = dot128(buf2, pW2, tid) + pb2r;
        outV[(size_t)p*SLOTF + tid] = vijv;    // fp32 vij stash in own slot

        // env branch (buf1 still v)
        const float he = ssp(dot128(buf1, eW1, tid) + eb1r);
        __syncthreads();
        buf2[tid] = he;
        __syncthreads();
        const float vikv = dot128(buf2, eW2, tid) + eb2r;

        const float c0 = cos_ij[p*3 + 0];
        const float c1 = cos_ij[p*3 + 1];
        const float c2 = cos_ij[p*3 + 2];
        vik0 += vikv * c0 * m;
        vik1 += vikv * c1 * m;
        vik2 += vikv * c2 * m;
    }

    // vi = mlp2(vsum, atom)
    __syncthreads();
    buf1[tid] = vsum;
    __syncthreads();
    const float ha = ssp(dot128(buf1, aW1, tid) + ab1[tid]);
    __syncthreads();
    buf2[tid] = ha;
    __syncthreads();
    const float viv = dot128(buf2, aW2, tid) + ab2[tid];
    out_vi[ba*NCB + tid] = viv;

    g_vik[ba*384 + tid*3 + 0] = vik0;
    g_vik[ba*384 + tid*3 + 1] = vik1;
    g_vik[ba*384 + tid*3 + 2] = vik2;
}

// finalize slot p: V[p,c,d] = vij[c]*cos[d] + g_vik[row a] + g_vik[row j]
__global__ __launch_bounds__(NF)
void k_V(const float* __restrict__ cos_ij, const int* __restrict__ neighbors,
         float* __restrict__ outV){
    const int p   = blockIdx.x;
    const int tid = threadIdx.x;
    const int b = p / (A*NN);
    const int a = (p / NN) % A;
    const int j = neighbors[p] & (A-1);

    float* slot = outV + (size_t)p*SLOTF;
    const float vij = slot[tid];
    const float c0 = cos_ij[p*3 + 0];
    const float c1 = cos_ij[p*3 + 1];
    const float c2 = cos_ij[p*3 + 2];

    const float* va = g_vik + (size_t)(b*A + a)*384 + tid*3;
    const float* vj = g_vik + (size_t)(b*A + j)*384 + tid*3;
    const float o0 = vij*c0 + va[0] + vj[0];
    const float o1 = vij*c1 + va[1] + vj[1];
    const float o2 = vij*c2 + va[2] + vj[2];

    __syncthreads();   // all vij stash reads complete before slot overwrite

    slot[tid*3 + 0] = o0;
    slot[tid*3 + 1] = o1;
    slot[tid*3 + 2] = o2;
}

extern "C" void kernel_launch(void* const* d_in, const int* in_sizes, int n_in,
                              void* d_out, int out_size, void* d_ws, size_t ws_size,
                              hipStream_t stream){
    const float* xi      = (const float*)d_in[0];
    const float* r_ij    = (const float*)d_in[1];
    const float* cos_ij  = (const float*)d_in[2];
    const float* f_ij    = (const float*)d_in[3];
    const float* nmask   = (const float*)d_in[4];
    const float* fW1     = (const float*)d_in[5];
    const float* fb1     = (const float*)d_in[6];
    const float* fW2     = (const float*)d_in[7];
    const float* fb2     = (const float*)d_in[8];
    const float* in2f_W  = (const float*)d_in[9];
    const float* f2W     = (const float*)d_in[10];
    const float* f2b     = (const float*)d_in[11];
    const float* aW1     = (const float*)d_in[12];
    const float* ab1     = (const float*)d_in[13];
    const float* aW2     = (const float*)d_in[14];
    const float* ab2     = (const float*)d_in[15];
    const float* pW1     = (const float*)d_in[16];
    const float* pb1     = (const float*)d_in[17];
    const float* pW2     = (const float*)d_in[18];
    const float* pb2     = (const float*)d_in[19];
    const float* eW1     = (const float*)d_in[20];
    const float* eb1     = (const float*)d_in[21];
    const float* eW2     = (const float*)d_in[22];
    const float* eb2     = (const float*)d_in[23];
    const int*  nbrs     = (const int*)d_in[24];

    float* out_vi = (float*)d_out;             // [B,A,NCB] fp32
    float* outV   = (float*)d_out + BA*NCB;    // [B,A,N,NCB,3] fp32

    k_yi<<<BA, NF, 0, stream>>>(xi, in2f_W);

    k_main<<<BA, NF, 0, stream>>>(r_ij, cos_ij, f_ij, nmask, nbrs,
                                  fW1, fb1, fW2, fb2, f2W, f2b,
                                  aW1, ab1, aW2, ab2,
                                  pW1, pb1, pW2, pb2,
                                  eW1, eb1, eW2, eb2,
                                  outV, out_vi);

    k_V<<<PAIRS, NF, 0, stream>>>(cos_ij, nbrs, outV);
}

// Round 7
// 343.179 us; speedup vs baseline: 3.3021x; 3.3021x over previous
//
#include <hip/hip_runtime.h>
#include <hip/hip_bf16.h>
#include <math.h>

#define B 4
#define A 256
#define NN 64
#define NCB 128
#define NF 128
#define NSB 50
#define BA (B*A)
#define PAIRS (BA*NN)

typedef __bf16 bf;
typedef __attribute__((ext_vector_type(8))) __bf16 bfrag8;
typedef __attribute__((ext_vector_type(4))) float ffrag4;

// ---- module-scope scratch (never touches inputs / d_ws) ----
__device__ __attribute__((aligned(16))) bf    g_yib[BA*NF];          // bf16(xi @ in2f_W)
__device__ __attribute__((aligned(16))) bf    g_vij[(size_t)PAIRS*NCB]; // bf16 vij stash (16 MB)
__device__ __attribute__((aligned(16))) float g_vik[BA*NCB*3];       // fp32 Vik rows [ba][c*3+d]
// transposed bf16 weights, layout [n][k] (k contiguous)
__device__ __attribute__((aligned(16))) bf g_tf1[NF*64];
__device__ __attribute__((aligned(16))) bf g_tf2[NF*NF];
__device__ __attribute__((aligned(16))) bf g_tfo[NF*NF];
__device__ __attribute__((aligned(16))) bf g_tp1[NF*NF];
__device__ __attribute__((aligned(16))) bf g_tp2[NF*NF];
__device__ __attribute__((aligned(16))) bf g_te1[NF*NF];
__device__ __attribute__((aligned(16))) bf g_te2[NF*NF];

__device__ __forceinline__ float ssp(float x){
    return fmaxf(x, 0.f) + log1pf(expf(-fabsf(x))) - 0.6931471805599453f;
}

// ---- weight pre-transpose: W[k][n] fp32 -> Wt[n][k] bf16 (pad k for filter W1) ----
__global__ __launch_bounds__(256)
void k_wt(const float* __restrict__ f1, const float* __restrict__ f2,
          const float* __restrict__ fo, const float* __restrict__ p1,
          const float* __restrict__ p2, const float* __restrict__ e1,
          const float* __restrict__ e2){
    int s = blockIdx.x;
    const float* src; bf* dst; int kb, realK;
    if (s == 0){ src = f1; dst = g_tf1; kb = 6; realK = NSB; }
    else {
        kb = 7; realK = 128;
        src = (s==1)?f2:(s==2)?fo:(s==3)?p1:(s==4)?p2:(s==5)?e1:e2;
        dst = (s==1)?g_tf2:(s==2)?g_tfo:(s==3)?g_tp1:(s==4)?g_tp2:(s==5)?g_te1:g_te2;
    }
    int total = NF << kb;
    for (int e = threadIdx.x; e < total; e += 256){
        int n = e >> kb, k = e & ((1<<kb)-1);
        dst[e] = (k < realK) ? (bf)src[k*NF + n] : (bf)0.f;
    }
}

// ---- g_yib[row][f] = bf16( xi[row,:] @ in2f_W[:,f] ) ----
__global__ __launch_bounds__(NF)
void k_yi(const float* __restrict__ xi, const float* __restrict__ W){
    int row = blockIdx.x, f = threadIdx.x;
    __shared__ float x[NCB];
    x[f] = xi[row*NCB + f];
    __syncthreads();
    float s = 0.f;
    #pragma unroll 16
    for (int c = 0; c < NCB; c++) s += x[c]*W[c*NF + f];
    g_yib[row*NF + f] = (bf)s;
}

// ---- LDS staging helpers ----
__device__ __forceinline__ void stage_w128(bf* __restrict__ sW, const bf* __restrict__ g,
                                           int half, int tid){
    // 64 n-rows x 128 k, LDS stride 136
    #pragma unroll
    for (int i = 0; i < 4; i++){
        int r  = i*16 + (tid >> 4);
        int cp = (tid & 15)*8;
        *(bfrag8*)&sW[r*136 + cp] = *(const bfrag8*)&g[(half*64 + r)*128 + cp];
    }
}
__device__ __forceinline__ void stage_w64(bf* __restrict__ sW, const bf* __restrict__ g,
                                          int half, int tid){
    // 64 n-rows x 64 k, LDS stride 72
    #pragma unroll
    for (int i = 0; i < 2; i++){
        int r  = i*32 + (tid >> 3);
        int cp = (tid & 7)*8;
        *(bfrag8*)&sW[r*72 + cp] = *(const bfrag8*)&g[(half*64 + r)*64 + cp];
    }
}
__device__ __forceinline__ void gemm4(const bf* __restrict__ sW, const bfrag8 afr[4],
                                      ffrag4 acc[4], int q, int c16){
    #pragma unroll
    for (int nt = 0; nt < 4; nt++){
        ffrag4 a = {0.f,0.f,0.f,0.f};
        #pragma unroll
        for (int kt = 0; kt < 4; kt++){
            bfrag8 bv = *(const bfrag8*)&sW[(nt*16 + c16)*136 + kt*32 + q*8];
            a = __builtin_amdgcn_mfma_f32_16x16x32_bf16(afr[kt], bv, a, 0, 0, 0);
        }
        acc[nt] = a;
    }
}
__device__ __forceinline__ void gemm2(const bf* __restrict__ sW, const bfrag8 afr[2],
                                      ffrag4 acc[4], int q, int c16){
    #pragma unroll
    for (int nt = 0; nt < 4; nt++){
        ffrag4 a = {0.f,0.f,0.f,0.f};
        #pragma unroll
        for (int kt = 0; kt < 2; kt++){
            bfrag8 bv = *(const bfrag8*)&sW[(nt*16 + c16)*72 + kt*32 + q*8];
            a = __builtin_amdgcn_mfma_f32_16x16x32_bf16(afr[kt], bv, a, 0, 0, 0);
        }
        acc[nt] = a;
    }
}

__global__ __launch_bounds__(256, 2)
void k_main(const float* __restrict__ r_ij, const float* __restrict__ cos_ij,
            const float* __restrict__ f_ij, const float* __restrict__ mask,
            const int* __restrict__ neighbors,
            const float* __restrict__ fb1, const float* __restrict__ fb2,
            const float* __restrict__ f2b,
            const float* __restrict__ aW1, const float* __restrict__ ab1,
            const float* __restrict__ aW2, const float* __restrict__ ab2,
            const float* __restrict__ pb1, const float* __restrict__ pb2,
            const float* __restrict__ eb1, const float* __restrict__ eb2,
            float* __restrict__ out_vi){
    const int tid  = threadIdx.x;
    const int ba   = blockIdx.x;          // atom (b*A + a)
    const int b    = ba >> 8;
    const int w    = tid >> 6;            // wave 0..3 -> m-tile (rows w*16..w*16+15)
    const int lane = tid & 63;
    const int q    = lane >> 4;
    const int c16  = lane & 15;
    const int arow = w*16 + c16;          // A-frag row for this lane

    __shared__ __attribute__((aligned(16))) bf sW [64*136];
    __shared__ __attribute__((aligned(16))) bf sA [64*136];   // h1/u/v
    __shared__ __attribute__((aligned(16))) bf sA2[64*136];   // f / hp / vij / he
    __shared__ float sCosM[64*4];   // cos0,cos1,cos2,mask
    __shared__ float sCr[64];
    __shared__ int   sJb[64];       // (b*A+j)*NF
    __shared__ float sVs[4*128];    // per-wave vsum partials
    __shared__ float sVk[4*384];    // per-wave Vik partials
    __shared__ float sVsum[128];
    __shared__ float sHa[128];

    // ---- preload: f -> sA2 (K padded to 64), per-pair scalars ----
    #pragma unroll
    for (int i = 0; i < 16; i++){
        int e = tid + i*256;                       // 64*64
        int row = e >> 6, col = e & 63;
        float v = (col < NSB) ? f_ij[(ba*64 + row)*NSB + col] : 0.f;
        sA2[row*136 + col] = (bf)v;
    }
    if (tid < 64){
        int p = ba*64 + tid;
        sCosM[tid*4+0] = cos_ij[p*3+0];
        sCosM[tid*4+1] = cos_ij[p*3+1];
        sCosM[tid*4+2] = cos_ij[p*3+2];
        sCosM[tid*4+3] = mask[p];
        float r = r_ij[p];
        sCr[tid] = (r < 5.f) ? 0.5f*(cosf(r*0.62831853071795864769f) + 1.f) : 0.f;
        int j = neighbors[p] & (A-1);
        sJb[tid] = (b*A + j)*NF;
    }
    __syncthreads();

    bfrag8 afr4[4]; bfrag8 afr2[2]; ffrag4 acc[4];

    // ================= S1: h1 = ssp(f @ fW1 + fb1) -> sA =================
    #pragma unroll
    for (int kt = 0; kt < 2; kt++) afr2[kt] = *(const bfrag8*)&sA2[arow*136 + kt*32 + q*8];
    #pragma unroll
    for (int half = 0; half < 2; half++){
        if (half) __syncthreads();
        stage_w64(sW, g_tf1, half, tid);
        __syncthreads();
        gemm2(sW, afr2, acc, q, c16);
        #pragma unroll
        for (int nt = 0; nt < 4; nt++){
            int col = (half*4 + nt)*16 + c16;
            float bias = fb1[col];
            #pragma unroll
            for (int rg = 0; rg < 4; rg++){
                int row = w*16 + q*4 + rg;
                sA[row*136 + col] = (bf)ssp(acc[nt][rg] + bias);
            }
        }
    }
    __syncthreads();

    // ===== S2: Wf = (h1 @ fW2 + fb2)*C ; u = yj*Wf -> sA (in-place) =====
    #pragma unroll
    for (int kt = 0; kt < 4; kt++) afr4[kt] = *(const bfrag8*)&sA[arow*136 + kt*32 + q*8];
    #pragma unroll
    for (int half = 0; half < 2; half++){
        if (half) __syncthreads();
        stage_w128(sW, g_tf2, half, tid);
        __syncthreads();
        gemm4(sW, afr4, acc, q, c16);
        #pragma unroll
        for (int nt = 0; nt < 4; nt++){
            int col = (half*4 + nt)*16 + c16;
            float bias = fb2[col];
            #pragma unroll
            for (int rg = 0; rg < 4; rg++){
                int row = w*16 + q*4 + rg;
                float wf = (acc[nt][rg] + bias) * sCr[row];
                float u  = (float)g_yib[sJb[row] + col] * wf;
                sA[row*136 + col] = (bf)u;
            }
        }
    }
    __syncthreads();

    // ===== S3: v = ssp(u @ f2W + f2b) -> sA (in-place); vsum partials =====
    float vsAll[8];
    #pragma unroll
    for (int t = 0; t < 8; t++) vsAll[t] = 0.f;
    #pragma unroll
    for (int kt = 0; kt < 4; kt++) afr4[kt] = *(const bfrag8*)&sA[arow*136 + kt*32 + q*8];
    #pragma unroll
    for (int half = 0; half < 2; half++){
        if (half) __syncthreads();
        stage_w128(sW, g_tfo, half, tid);
        __syncthreads();
        gemm4(sW, afr4, acc, q, c16);
        #pragma unroll
        for (int nt = 0; nt < 4; nt++){
            int col = (half*4 + nt)*16 + c16;
            float bias = f2b[col];
            #pragma unroll
            for (int rg = 0; rg < 4; rg++){
                int row = w*16 + q*4 + rg;
                float v = ssp(acc[nt][rg] + bias);
                sA[row*136 + col] = (bf)v;
                vsAll[half*4 + nt] += v * sCosM[row*4+3];
            }
        }
    }
    #pragma unroll
    for (int t = 0; t < 8; t++){
        float v = vsAll[t];
        v += __shfl_xor(v, 16);
        v += __shfl_xor(v, 32);
        if (q == 0) sVs[w*128 + t*16 + c16] = v;
    }
    __syncthreads();

    // ================= S4: hp = ssp(v @ pW1 + pb1) -> sA2 =================
    #pragma unroll
    for (int kt = 0; kt < 4; kt++) afr4[kt] = *(const bfrag8*)&sA[arow*136 + kt*32 + q*8];
    #pragma unroll
    for (int half = 0; half < 2; half++){
        if (half) __syncthreads();
        stage_w128(sW, g_tp1, half, tid);
        __syncthreads();
        gemm4(sW, afr4, acc, q, c16);
        #pragma unroll
        for (int nt = 0; nt < 4; nt++){
            int col = (half*4 + nt)*16 + c16;
            float bias = pb1[col];
            #pragma unroll
            for (int rg = 0; rg < 4; rg++){
                int row = w*16 + q*4 + rg;
                sA2[row*136 + col] = (bf)ssp(acc[nt][rg] + bias);
            }
        }
    }
    __syncthreads();

    // ============ S5: vij = hp @ pW2 + pb2 -> sA2 (in-place, bf16) ============
    #pragma unroll
    for (int kt = 0; kt < 4; kt++) afr4[kt] = *(const bfrag8*)&sA2[arow*136 + kt*32 + q*8];
    #pragma unroll
    for (int half = 0; half < 2; half++){
        if (half) __syncthreads();
        stage_w128(sW, g_tp2, half, tid);
        __syncthreads();
        gemm4(sW, afr4, acc, q, c16);
        #pragma unroll
        for (int nt = 0; nt < 4; nt++){
            int col = (half*4 + nt)*16 + c16;
            float bias = pb2[col];
            #pragma unroll
            for (int rg = 0; rg < 4; rg++){
                int row = w*16 + q*4 + rg;
                sA2[row*136 + col] = (bf)(acc[nt][rg] + bias);
            }
        }
    }
    __syncthreads();

    // ===== S6: copy vij -> g_vij; he = ssp(v @ eW1 + eb1) -> sA2 =====
    #pragma unroll
    for (int i = 0; i < 4; i++){
        int row = i*16 + (tid >> 4);
        int cp  = (tid & 15)*8;
        *(bfrag8*)&g_vij[((size_t)ba*64 + row)*128 + cp] = *(const bfrag8*)&sA2[row*136 + cp];
    }
    #pragma unroll
    for (int kt = 0; kt < 4; kt++) afr4[kt] = *(const bfrag8*)&sA[arow*136 + kt*32 + q*8];
    #pragma unroll
    for (int half = 0; half < 2; half++){
        if (half) __syncthreads();
        stage_w128(sW, g_te1, half, tid);
        __syncthreads();
        gemm4(sW, afr4, acc, q, c16);
        #pragma unroll
        for (int nt = 0; nt < 4; nt++){
            int col = (half*4 + nt)*16 + c16;
            float bias = eb1[col];
            #pragma unroll
            for (int rg = 0; rg < 4; rg++){
                int row = w*16 + q*4 + rg;
                sA2[row*136 + col] = (bf)ssp(acc[nt][rg] + bias);
            }
        }
    }
    __syncthreads();

    // ===== S7: vik = he @ eW2 + eb2 ; Vik partials (no act write) =====
    float vkAll[8][3];
    #pragma unroll
    for (int t = 0; t < 8; t++){ vkAll[t][0]=0.f; vkAll[t][1]=0.f; vkAll[t][2]=0.f; }
    #pragma unroll
    for (int kt = 0; kt < 4; kt++) afr4[kt] = *(const bfrag8*)&sA2[arow*136 + kt*32 + q*8];
    #pragma unroll
    for (int half = 0; half < 2; half++){
        if (half) __syncthreads();
        stage_w128(sW, g_te2, half, tid);
        __syncthreads();
        gemm4(sW, afr4, acc, q, c16);
        #pragma unroll
        for (int nt = 0; nt < 4; nt++){
            int col = (half*4 + nt)*16 + c16; (void)col;
            float bias = eb2[(half*4 + nt)*16 + c16];
            #pragma unroll
            for (int rg = 0; rg < 4; rg++){
                int row = w*16 + q*4 + rg;
                float vik = (acc[nt][rg] + bias) * sCosM[row*4+3];
                vkAll[half*4 + nt][0] += vik * sCosM[row*4+0];
                vkAll[half*4 + nt][1] += vik * sCosM[row*4+1];
                vkAll[half*4 + nt][2] += vik * sCosM[row*4+2];
            }
        }
    }
    #pragma unroll
    for (int t = 0; t < 8; t++){
        #pragma unroll
        for (int d = 0; d < 3; d++){
            float v = vkAll[t][d];
            v += __shfl_xor(v, 16);
            v += __shfl_xor(v, 32);
            if (q == 0) sVk[w*384 + (t*16 + c16)*3 + d] = v;
        }
    }
    __syncthreads();

    // ===== finale: Vik out + vi = mlp2(vsum, atom) =====
    for (int e = tid; e < 384; e += 256)
        g_vik[ba*384 + e] = sVk[e] + sVk[384+e] + sVk[768+e] + sVk[1152+e];
    if (tid < 128)
        sVsum[tid] = sVs[tid] + sVs[128+tid] + sVs[256+tid] + sVs[384+tid];
    __syncthreads();
    if (tid < 128){
        float acc2 = ab1[tid];
        #pragma unroll 16
        for (int k = 0; k < 128; k++) acc2 += sVsum[k]*aW1[k*128 + tid];
        sHa[tid] = ssp(acc2);
    }
    __syncthreads();
    if (tid < 128){
        float acc2 = ab2[tid];
        #pragma unroll 16
        for (int k = 0; k < 128; k++) acc2 += sHa[k]*aW2[k*128 + tid];
        out_vi[ba*128 + tid] = acc2;
    }
}

// ---- V[p,c,d] = vij[p,c]*cos[p,d] + Vik[ba] + Vik[j-row], coalesced fp32 out ----
__global__ __launch_bounds__(128)
void k_V(const float* __restrict__ cos_ij, const int* __restrict__ nbrs,
         float* __restrict__ outV){
    const int p = blockIdx.x, t = threadIdx.x;
    const int ba = p >> 6;
    const int b  = ba >> 8;
    const int rj = b*A + (nbrs[p] & (A-1));
    __shared__ float sVC[384];
    float vv = (float)g_vij[(size_t)p*128 + t];
    float c0 = cos_ij[p*3+0], c1 = cos_ij[p*3+1], c2 = cos_ij[p*3+2];
    sVC[t*3+0] = vv*c0; sVC[t*3+1] = vv*c1; sVC[t*3+2] = vv*c2;
    __syncthreads();
    const float* va = g_vik + (size_t)ba*384;
    const float* vj = g_vik + (size_t)rj*384;
    #pragma unroll
    for (int i = 0; i < 3; i++){
        int e = i*128 + t;
        outV[(size_t)p*384 + e] = sVC[e] + va[e] + vj[e];
    }
}

extern "C" void kernel_launch(void* const* d_in, const int* in_sizes, int n_in,
                              void* d_out, int out_size, void* d_ws, size_t ws_size,
                              hipStream_t stream){
    const float* xi      = (const float*)d_in[0];
    const float* r_ij    = (const float*)d_in[1];
    const float* cos_ij  = (const float*)d_in[2];
    const float* f_ij    = (const float*)d_in[3];
    const float* nmask   = (const float*)d_in[4];
    const float* fW1     = (const float*)d_in[5];
    const float* fb1     = (const float*)d_in[6];
    const float* fW2     = (const float*)d_in[7];
    const float* fb2     = (const float*)d_in[8];
    const float* in2f_W  = (const float*)d_in[9];
    const float* f2W     = (const float*)d_in[10];
    const float* f2b     = (const float*)d_in[11];
    const float* aW1     = (const float*)d_in[12];
    const float* ab1     = (const float*)d_in[13];
    const float* aW2     = (const float*)d_in[14];
    const float* ab2     = (const float*)d_in[15];
    const float* pW1     = (const float*)d_in[16];
    const float* pb1     = (const float*)d_in[17];
    const float* pW2     = (const float*)d_in[18];
    const float* pb2     = (const float*)d_in[19];
    const float* eW1     = (const float*)d_in[20];
    const float* eb1     = (const float*)d_in[21];
    const float* eW2     = (const float*)d_in[22];
    const float* eb2     = (const float*)d_in[23];
    const int*  nbrs     = (const int*)d_in[24];

    float* out_vi = (float*)d_out;             // [B,A,NCB] fp32
    float* outV   = (float*)d_out + BA*NCB;    // [B,A,N,NCB,3] fp32

    k_wt<<<7, 256, 0, stream>>>(fW1, fW2, f2W, pW1, pW2, eW1, eW2);
    k_yi<<<BA, NF, 0, stream>>>(xi, in2f_W);

    k_main<<<BA, 256, 0, stream>>>(r_ij, cos_ij, f_ij, nmask, nbrs,
                                   fb1, fb2, f2b,
                                   aW1, ab1, aW2, ab2,
                                   pb1, pb2, eb1, eb2,
                                   out_vi);

    k_V<<<PAIRS, 128, 0, stream>>>(cos_ij, nbrs, outV);
}